// Round 2
// baseline (84.988 us; speedup 1.0000x reference)
//
#include <hip/hip_runtime.h>

// Problem constants (match reference)
#define B_ 16
#define F_ 256
#define N_ 16384
#define L_ 4096
#define K_ 9

// ---------------------------------------------------------------------------
// Pre-pass: fold mask into index, pack 9 indices (+7 pad) as 16 ushorts per l
// (32 B, 16B-aligned). masked (mask==0) -> sentinel index N_ (row[N_]==0.0f).
// Pad slots also get N_ but are never gathered.
// ---------------------------------------------------------------------------
__global__ __launch_bounds__(256) void prep_comb_kernel(
    const int* __restrict__ idx, const float* __restrict__ mask,
    unsigned short* __restrict__ comb) {
  int l = blockIdx.x * blockDim.x + threadIdx.x;  // over L_
  if (l >= L_) return;
  unsigned short v[16];
#pragma unroll
  for (int k = 0; k < 16; ++k) v[k] = (unsigned short)N_;
#pragma unroll
  for (int k = 0; k < K_; ++k) {
    int t = l * K_ + k;
    int id = idx[t];
    float m = mask[t];
    v[k] = (m != 0.0f) ? (unsigned short)id : (unsigned short)N_;
  }
  uint4* dst = (uint4*)(comb) + (size_t)l * 2;
  dst[0] = make_uint4(((unsigned)v[1] << 16) | v[0], ((unsigned)v[3] << 16) | v[2],
                      ((unsigned)v[5] << 16) | v[4], ((unsigned)v[7] << 16) | v[6]);
  dst[1] = make_uint4(((unsigned)v[9] << 16) | v[8], ((unsigned)v[11] << 16) | v[10],
                      ((unsigned)v[13] << 16) | v[12], ((unsigned)v[15] << 16) | v[14]);
}

// ---------------------------------------------------------------------------
// Main kernel: one block (1024 threads) per (b,f) row. Stage the 64 KiB row
// in LDS (+0.0f sentinel at slot N_), then 9 LDS gathers + max per output.
// LDS = 65.6 KiB -> 2 blocks/CU -> 32 waves/CU (full occupancy).
// ---------------------------------------------------------------------------
__global__ __launch_bounds__(1024) void pool_kernel(
    const float* __restrict__ img, const unsigned short* __restrict__ comb,
    float* __restrict__ out) {
  __shared__ __align__(16) float row[N_ + 4];  // sentinel at row[N_]
  const int bf = blockIdx.x;  // 0 .. B_*F_-1
  const int tid = threadIdx.x;

  // Stage row: 16384 floats = 4096 float4; 1024 threads -> 4 float4 each.
  const float4* src4 = (const float4*)(img + (size_t)bf * N_);
  float4* row4 = (float4*)row;
#pragma unroll
  for (int i = 0; i < 4; ++i) {
    int j = i * 1024 + tid;
    row4[j] = src4[j];
  }
  if (tid == 0) row[N_] = 0.0f;
  __syncthreads();

  float* outp = out + (size_t)bf * L_;
#pragma unroll
  for (int it = 0; it < L_ / 1024; ++it) {
    int l = it * 1024 + tid;
    const uint4* c = (const uint4*)(comb) + (size_t)l * 2;
    uint4 a = c[0];
    uint4 b = c[1];
    float v0 = row[a.x & 0xffffu];
    float v1 = row[a.x >> 16];
    float v2 = row[a.y & 0xffffu];
    float v3 = row[a.y >> 16];
    float v4 = row[a.z & 0xffffu];
    float v5 = row[a.z >> 16];
    float v6 = row[a.w & 0xffffu];
    float v7 = row[a.w >> 16];
    float v8 = row[b.x & 0xffffu];
    // max3-friendly tree (clang fuses nested fmaxf to v_max3_f32)
    float t0 = fmaxf(fmaxf(v0, v1), v2);
    float t1 = fmaxf(fmaxf(v3, v4), v5);
    float t2 = fmaxf(fmaxf(v6, v7), v8);
    outp[l] = fmaxf(fmaxf(t0, t1), t2);  // coalesced
  }
}

// ---------------------------------------------------------------------------
// Fallback (ws too small): read raw indices + mask directly.
// ---------------------------------------------------------------------------
__global__ __launch_bounds__(256) void pool_kernel_direct(
    const float* __restrict__ img, const int* __restrict__ idx,
    const float* __restrict__ mask, float* __restrict__ out) {
  __shared__ __align__(16) float row[N_ + 4];
  const int bf = blockIdx.x;
  const int tid = threadIdx.x;

  const float4* src4 = (const float4*)(img + (size_t)bf * N_);
  float4* row4 = (float4*)row;
#pragma unroll
  for (int i = 0; i < 16; ++i) {
    int j = i * 256 + tid;
    row4[j] = src4[j];
  }
  __syncthreads();

  float* outp = out + (size_t)bf * L_;
  for (int it = 0; it < L_ / 256; ++it) {
    int l = it * 256 + tid;
    float m = -INFINITY;
#pragma unroll
    for (int k = 0; k < K_; ++k) {
      int t = l * K_ + k;
      float v = (mask[t] != 0.0f) ? row[idx[t]] : 0.0f;
      m = fmaxf(m, v);
    }
    outp[l] = m;
  }
}

extern "C" void kernel_launch(void* const* d_in, const int* in_sizes, int n_in,
                              void* d_out, int out_size, void* d_ws, size_t ws_size,
                              hipStream_t stream) {
  const float* img = (const float*)d_in[0];
  const int* idx = (const int*)d_in[1];
  const float* mask = (const float*)d_in[2];
  float* out = (float*)d_out;

  const size_t comb_bytes = (size_t)L_ * 16 * sizeof(unsigned short);
  if (ws_size >= comb_bytes) {
    unsigned short* comb = (unsigned short*)d_ws;
    prep_comb_kernel<<<(L_ + 255) / 256, 256, 0, stream>>>(idx, mask, comb);
    pool_kernel<<<B_ * F_, 1024, 0, stream>>>(img, comb, out);
  } else {
    pool_kernel_direct<<<B_ * F_, 256, 0, stream>>>(img, idx, mask, out);
  }
}